// Round 1
// baseline (822.038 us; speedup 1.0000x reference)
//
#include <hip/hip_runtime.h>

// ---------------------------------------------------------------------------
// OHEM cross-entropy: losses[i] = logsumexp(pred[i,:]) - pred[i, target[i]]
// then mean of the top keep_num = int(0.7*N) losses.
// Exact top-k sum via 4-pass radix-256 select on float bit patterns
// (valid because losses are clamped >= +0, where uint order == float order).
// ---------------------------------------------------------------------------

__global__ __launch_bounds__(256) void init_k(unsigned* hist, unsigned* state,
                                              double* sum_gt, int k) {
    int t = threadIdx.x;
    hist[t] = 0u;
    if (t == 0) {
        state[0] = 0u;           // prefix (bit pattern of k-th largest, built MSB->LSB)
        state[1] = (unsigned)k;  // remaining rank
        state[2] = 0u;           // cnt_gt
        *sum_gt  = 0.0;          // sum of losses > t
    }
}

// one 64-lane wave per row; C = 128 -> float2 per lane
__global__ __launch_bounds__(256) void loss_k(const float* __restrict__ pred,
                                              const int* __restrict__ target,
                                              float* __restrict__ losses, int N) {
    int wave = threadIdx.x >> 6;
    int lane = threadIdx.x & 63;
    int row  = blockIdx.x * 4 + wave;
    if (row >= N) return;

    const float2* rp = (const float2*)(pred + (size_t)row * 128);
    float2 v = rp[lane];

    float m = fmaxf(v.x, v.y);
    #pragma unroll
    for (int off = 32; off >= 1; off >>= 1) m = fmaxf(m, __shfl_xor(m, off));

    float e = expf(v.x - m) + expf(v.y - m);
    #pragma unroll
    for (int off = 32; off >= 1; off >>= 1) e += __shfl_xor(e, off);

    int t = target[row];                 // wave-uniform
    float xs = (t & 1) ? v.y : v.x;      // component select (t uniform across wave)
    float xt = __shfl(xs, t >> 1);       // broadcast from owning lane

    float loss = logf(e) + m - xt;       // >= 0 mathematically
    loss = fmaxf(loss, 0.0f);            // kill tiny negative rounding (keeps uint order valid)

    if (lane == 0) losses[row] = loss;
}

// histogram of byte (u >> shift) among values whose high bits match prefix
__global__ __launch_bounds__(256) void hist_k(const unsigned* __restrict__ lu,
                                              unsigned* __restrict__ hist,
                                              const unsigned* __restrict__ state,
                                              int N, int shift, unsigned mask) {
    __shared__ unsigned h[256];
    h[threadIdx.x] = 0u;
    __syncthreads();
    unsigned prefix = state[0];          // only bits above (shift+8) are set
    int stride = gridDim.x * blockDim.x;
    for (int i = blockIdx.x * blockDim.x + threadIdx.x; i < N; i += stride) {
        unsigned u = lu[i];
        if ((u & mask) == prefix)
            atomicAdd(&h[(u >> shift) & 255u], 1u);
    }
    __syncthreads();
    unsigned c = h[threadIdx.x];
    if (c) atomicAdd(&hist[threadIdx.x], c);
}

// single block: suffix-sum from the top, pick digit where rank falls, update state
__global__ __launch_bounds__(256) void scan_k(unsigned* hist, unsigned* state, int shift) {
    __shared__ unsigned s[256];
    __shared__ unsigned suf[256];
    int t = threadIdx.x;
    unsigned rank = state[1];            // read BEFORE any write (barriers below order it)
    unsigned c = hist[t];
    s[t] = c;
    suf[t] = c;
    __syncthreads();
    #pragma unroll
    for (int step = 1; step < 256; step <<= 1) {
        unsigned v = (t + step < 256) ? suf[t + step] : 0u;
        __syncthreads();
        suf[t] += v;
        __syncthreads();
    }
    unsigned incl = suf[t];              // count of values with digit >= t
    unsigned excl = incl - s[t];         // count of values with digit >  t
    if (excl < rank && rank <= incl) {   // exactly one t satisfies this
        state[0] |= ((unsigned)t) << shift;
        state[1] = rank - excl;
    }
    hist[t] = 0u;                        // ready for next pass
}

__global__ __launch_bounds__(256) void final_k(const unsigned* __restrict__ lu,
                                               const unsigned* __restrict__ state,
                                               unsigned* cnt_gt, double* sum_gt, int N) {
    unsigned tu = state[0];
    double s = 0.0;
    unsigned c = 0;
    int stride = gridDim.x * blockDim.x;
    for (int i = blockIdx.x * blockDim.x + threadIdx.x; i < N; i += stride) {
        unsigned u = lu[i];
        if (u > tu) { s += (double)__uint_as_float(u); c++; }
    }
    __shared__ double sd[256];
    __shared__ unsigned sc[256];
    sd[threadIdx.x] = s;
    sc[threadIdx.x] = c;
    __syncthreads();
    for (int step = 128; step >= 1; step >>= 1) {
        if (threadIdx.x < step) {
            sd[threadIdx.x] += sd[threadIdx.x + step];
            sc[threadIdx.x] += sc[threadIdx.x + step];
        }
        __syncthreads();
    }
    if (threadIdx.x == 0) {
        atomicAdd(cnt_gt, sc[0]);
        atomicAdd(sum_gt, sd[0]);
    }
}

__global__ void finalize_k(const unsigned* state, const unsigned* cnt_gt,
                           const double* sum_gt, float* out, int k) {
    double t = (double)__uint_as_float(state[0]);
    double s = *sum_gt + (double)(k - (int)*cnt_gt) * t;   // ties at t contribute t each
    out[0] = (float)(s / (double)k);
}

extern "C" void kernel_launch(void* const* d_in, const int* in_sizes, int n_in,
                              void* d_out, int out_size, void* d_ws, size_t ws_size,
                              hipStream_t stream) {
    const float* pred  = (const float*)d_in[0];
    const int* target  = (const int*)d_in[1];
    int N = in_sizes[1];                       // pred is [N,128]
    int k = (int)((double)N * 0.7);            // matches python int(N*0.7)

    float*    losses = (float*)d_ws;
    unsigned* lu     = (unsigned*)d_ws;
    unsigned* hist   = (unsigned*)((char*)d_ws + (size_t)N * 4);
    unsigned* state  = hist + 256;             // [0]=prefix [1]=rank [2]=cnt_gt [3]=pad
    double*   sum_gt = (double*)(state + 4);   // 8-byte aligned (N*4 + 1024 + 16)

    init_k<<<1, 256, 0, stream>>>(hist, state, sum_gt, k);
    loss_k<<<(N + 3) / 4, 256, 0, stream>>>(pred, target, losses, N);

    const int      shifts[4] = {24, 16, 8, 0};
    const unsigned masks[4]  = {0u, 0xFF000000u, 0xFFFF0000u, 0xFFFFFF00u};
    for (int p = 0; p < 4; p++) {
        hist_k<<<256, 256, 0, stream>>>(lu, hist, state, N, shifts[p], masks[p]);
        scan_k<<<1, 256, 0, stream>>>(hist, state, shifts[p]);
    }

    final_k<<<512, 256, 0, stream>>>(lu, state, state + 2, sum_gt, N);
    finalize_k<<<1, 1, 0, stream>>>(state, state + 2, sum_gt, (float*)d_out, k);
}